// Round 6
// baseline (707.753 us; speedup 1.0000x reference)
//
#include <hip/hip_runtime.h>

typedef unsigned short u16;
typedef __bf16 bf16x8 __attribute__((ext_vector_type(8)));
typedef float f32x4 __attribute__((ext_vector_type(4)));
typedef u16 u16x4 __attribute__((ext_vector_type(4)));

#define D_ 1024
#define T_ 2048
#define B_ 4
#define K_ 8
#define R_ 16
#define H_ 4096
#define NROW (B_*T_)
#define CH 32
#define CL (T_/CH)
#define CHS 64
#define CLS (T_/CHS)

__device__ __forceinline__ u16 f2bf(float f){
  union{float f;unsigned u;} v; v.f=f;
  unsigned r = v.u + 0x7FFFu + ((v.u>>16)&1u);
  return (u16)(r>>16);
}
__device__ __forceinline__ float bf2f(u16 b){
  union{unsigned u;float f;} v; v.u = ((unsigned)b)<<16; return v.f;
}
__device__ __forceinline__ float sigm(float x){ return 1.f/(1.f+__expf(-x)); }

__device__ __forceinline__ void gload_lds16(const void* g, void* l){
  __builtin_amdgcn_global_load_lds((const __attribute__((address_space(1))) void*)g,
                                   (__attribute__((address_space(3))) void*)l, 16, 0, 0);
}

__global__ __launch_bounds__(256) void fill_k(float* __restrict__ out, long n, float v){
  long i = (long)blockIdx.x*256 + threadIdx.x;
  if (i < n) out[i] = v;
}

// ---------------- weight prep ----------------
__global__ __launch_bounds__(256) void transpose_cast(const float* __restrict__ in, u16* __restrict__ out,
                                                      int R, int C){
  __shared__ float tile[32][33];
  int bx = blockIdx.x*32;
  int by = blockIdx.y*32;
  int tx = threadIdx.x & 31, ty = threadIdx.x >> 5;
  #pragma unroll
  for (int i=0;i<32;i+=8) tile[ty+i][tx] = in[(size_t)(by+ty+i)*C + bx+tx];
  __syncthreads();
  #pragma unroll
  for (int i=0;i<32;i+=8) out[(size_t)(bx+ty+i)*R + by+tx] = f2bf(tile[tx][ty+i]);
}

__global__ __launch_bounds__(256) void castbf(const float* __restrict__ in, u16* __restrict__ out, long n){
  long i = (long)blockIdx.x*256 + threadIdx.x;
  if (i < n) out[i] = f2bf(in[i]);
}

// out = x + dn_b (fp32, float4)
__global__ __launch_bounds__(256) void initout_k(const float* __restrict__ x, const float* __restrict__ b,
                                                 float* __restrict__ out){
  size_t i = ((size_t)blockIdx.x*256 + threadIdx.x)*4;
  f32x4 xv = *(const f32x4*)(x + i);
  f32x4 bv = *(const f32x4*)(b + (i & (D_-1)));
  xv += bv;
  *(f32x4*)(out + i) = xv;
}

// ---------------- rmsnorm ----------------
__global__ __launch_bounds__(256) void rmsnorm_k(const float* __restrict__ x, u16* __restrict__ u){
  int row = blockIdx.x;
  const float* xr = x + (size_t)row*D_;
  float xv[4]; float ss = 0.f;
  #pragma unroll
  for (int i=0;i<4;i++){ xv[i] = xr[threadIdx.x + 256*i]; ss += xv[i]*xv[i]; }
  #pragma unroll
  for (int o=32;o>0;o>>=1) ss += __shfl_down(ss, o);
  __shared__ float red[4];
  if ((threadIdx.x&63)==0) red[threadIdx.x>>6] = ss;
  __syncthreads();
  float tot = red[0]+red[1]+red[2]+red[3];
  float r = rsqrtf(tot*(1.f/D_) + 1e-6f);
  #pragma unroll
  for (int i=0;i<4;i++) u[(size_t)row*D_ + threadIdx.x + 256*i] = f2bf(xv[i]*r);
}

// ---------------- causal depthwise conv (KC=4), 4-wide ----------------
__global__ __launch_bounds__(256) void conv_k(const u16* __restrict__ u, const float* __restrict__ w,
                                              u16* __restrict__ xc){
  size_t base = ((size_t)blockIdx.x*256 + threadIdx.x)*4;
  int t  = (int)((base >> 10) & (T_-1));
  int d0 = (int)(base & (D_-1));
  f32x4 wv[4];
  #pragma unroll
  for (int jj=0;jj<4;jj++) wv[jj] = *(const f32x4*)&w[(d0+jj)*4];
  float acc[4] = {0.f,0.f,0.f,0.f};
  #pragma unroll
  for (int j=0;j<4;j++){
    if (t-3+j >= 0){
      u16x4 uv = *(const u16x4*)(u + base + (long)(j-3)*D_);
      #pragma unroll
      for (int jj=0;jj<4;jj++) acc[jj] += bf2f(uv[jj]) * wv[jj][j];
    }
  }
  u16x4 o;
  #pragma unroll
  for (int jj=0;jj<4;jj++) o[jj] = f2bf(acc[jj]);
  *(u16x4*)(xc + base) = o;
}

// ---------------- small-N projections ----------------
__global__ __launch_bounds__(256) void smalln_k(const u16* __restrict__ u,
    const float* __restrict__ rs_w, const float* __restrict__ rs_b,
    const float* __restrict__ rwg_w, const float* __restrict__ rwg_b,
    const float* __restrict__ gl_w, const float* __restrict__ gl_b,
    const float* __restrict__ gr_w, const float* __restrict__ gr_b,
    float* __restrict__ sel, float* __restrict__ wg, float* __restrict__ gl, float* __restrict__ gr){
  int row = blockIdx.x, tid = threadIdx.x;
  float p[19];
  #pragma unroll
  for (int c=0;c<19;c++) p[c] = 0.f;
  for (int i=0;i<4;i++){
    int e = tid + i*256;
    float ue = bf2f(u[(size_t)row*D_ + e]);
    const float* rw = rs_w + (size_t)e*16;
    #pragma unroll
    for (int r=0;r<16;r++) p[r] += ue*rw[r];
    p[16] += ue*rwg_w[e];
    p[17] += ue*gl_w[e];
    p[18] += ue*gr_w[e];
  }
  __shared__ float red[19*4];
  #pragma unroll
  for (int c=0;c<19;c++){
    float v = p[c];
    #pragma unroll
    for (int o=32;o>0;o>>=1) v += __shfl_down(v, o);
    if ((tid&63)==0) red[c*4 + (tid>>6)] = v;
  }
  __syncthreads();
  if (tid==0){
    float s[19];
    #pragma unroll
    for (int c=0;c<19;c++) s[c] = red[c*4]+red[c*4+1]+red[c*4+2]+red[c*4+3];
    float mx = -1e30f;
    #pragma unroll
    for (int r=0;r<16;r++){ s[r] += rs_b[r]; mx = fmaxf(mx, s[r]); }
    float ssum = 0.f;
    #pragma unroll
    for (int r=0;r<16;r++){ s[r] = __expf(s[r]-mx); ssum += s[r]; }
    float inv = 1.f/ssum;
    #pragma unroll
    for (int r=0;r<16;r++) sel[(size_t)row*16+r] = s[r]*inv;
    wg[row] = sigm(s[16] + rwg_b[0]);
    gl[row] = sigm(s[17] + gl_b[0]);
    gr[row] = sigm(s[18] + gr_b[0]);
  }
}

// ---------------- 128x128 MFMA GEMM (fallback path only) ----------------
#define BM 128
#define BN 128
#define BK 32

template<int EPI>
__global__ __launch_bounds__(256)
void gemm_bt(const u16* __restrict__ A, const u16* __restrict__ BT,
             void* __restrict__ outp, const float* __restrict__ bias,
             const void* __restrict__ aux,
             int K, int lda, int ldb, int ldc,
             long zA, long zB, long zC)
{
  __shared__ __attribute__((aligned(16))) u16 As[BM*BK];
  __shared__ __attribute__((aligned(16))) u16 Bs[BN*BK];
  int nwg = gridDim.x*gridDim.y;
  int bx = blockIdx.x, by = blockIdx.y;
  if ((nwg & 7) == 0){
    int bid = blockIdx.y*gridDim.x + blockIdx.x;
    int cpx = nwg >> 3;
    int s = (bid & 7)*cpx + (bid >> 3);
    bx = s % gridDim.x; by = s / gridDim.x;
  }
  const u16* Ab = A + (size_t)blockIdx.z*zA + (size_t)bx*BM*lda;
  const u16* Bb = BT + (size_t)blockIdx.z*zB + (size_t)by*BN*ldb;
  int tid = threadIdx.x, lane = tid&63, wid = tid>>6;
  int wr = wid>>1, wc = wid&1;
  f32x4 acc[4][4];
  #pragma unroll
  for (int m=0;m<4;m++)
    #pragma unroll
    for (int n=0;n<4;n++) acc[m][n] = (f32x4){0.f,0.f,0.f,0.f};

  int srow = lane>>2;
  int scol = (lane&3)*8;
  int klo  = (lane>>4)*8;
  for (int k0=0; k0<K; k0+=BK){
    #pragma unroll
    for (int i=0;i<2;i++){
      int r0 = wid*32 + i*16;
      gload_lds16(Ab + (size_t)(r0+srow)*lda + k0 + scol, &As[r0*BK]);
      gload_lds16(Bb + (size_t)(r0+srow)*ldb + k0 + scol, &Bs[r0*BK]);
    }
    __syncthreads();
    bf16x8 af[4], bfr[4];
    #pragma unroll
    for (int m=0;m<4;m++) af[m] = *(const bf16x8*)&As[(wr*64+m*16+(lane&15))*BK + klo];
    #pragma unroll
    for (int n=0;n<4;n++) bfr[n] = *(const bf16x8*)&Bs[(wc*64+n*16+(lane&15))*BK + klo];
    #pragma unroll
    for (int m=0;m<4;m++)
      #pragma unroll
      for (int n=0;n<4;n++)
        acc[m][n] = __builtin_amdgcn_mfma_f32_16x16x32_bf16(af[m], bfr[n], acc[m][n], 0, 0, 0);
    __syncthreads();
  }

  size_t obase = (size_t)blockIdx.z*zC;
  int row0 = bx*BM + wr*64;
  int col0 = by*BN + wc*64;
  #pragma unroll
  for (int m=0;m<4;m++){
    #pragma unroll
    for (int n=0;n<4;n++){
      int col = col0 + n*16 + (lane&15);
      #pragma unroll
      for (int r=0;r<4;r++){
        int row = row0 + m*16 + (lane>>4)*4 + r;
        float c = acc[m][n][r];
        size_t idx = obase + (size_t)row*ldc + col;
        if (EPI==0){ ((u16*)outp)[idx] = f2bf(c); }
        else if (EPI==1){ ((u16*)outp)[idx] = f2bf(c + bias[col]); }
        else if (EPI==2){ float t=c+bias[col]; ((u16*)outp)[idx] = f2bf(bf2f(((const u16*)aux)[idx]) * sigm(t)); }
        else if (EPI==3){ float t=c+bias[col]; ((u16*)outp)[idx] = f2bf(t*sigm(t)); }
        else if (EPI==4){ ((float*)outp)[idx] = ((const float*)aux)[idx] + c + bias[col]; }
        else            { ((float*)outp)[idx] += c; }
      }
    }
  }
}

// ---------------- 256x256 8-phase GEMM (CONTROL: unchanged schedule) ----------------
template<int NT, int EPI>
__global__ __launch_bounds__(512, 2)
void gemm8p(const u16* __restrict__ A, const u16* __restrict__ BT,
            void* __restrict__ outp, const float* __restrict__ bias,
            const void* __restrict__ aux,
            int lda, int ldb, int ldc, long zA, long zB, long zC,
            int rx, int ry, int nry)
{
  __shared__ __attribute__((aligned(16))) u16 lds8[65536];   // 128 KiB
  int bid = blockIdx.y*gridDim.x + blockIdx.x;
  int xcd = bid & 7;
  int s   = bid >> 3;
  int rgx = xcd / nry, rgy = xcd - rgx*nry;
  int bx = rgx*rx + (s % rx);
  int by = rgy*ry + (s / rx);

  const u16* Ab = A + (size_t)blockIdx.z*zA + (size_t)bx*256*lda;
  const u16* Bb = BT + (size_t)blockIdx.z*zB + (size_t)by*256*ldb;

  int tid = threadIdx.x, l = tid&63, w = tid>>6;
  int wr = w>>2, wc = w&3;
  int rS0 = (w*2+0)*8 + (l>>3);
  int rS1 = (w*2+1)*8 + (l>>3);
  int cg  = (((l&7) ^ (l>>3)) << 3);
  int seg0 = (w*2+0)*512;
  int seg1 = (w*2+1)*512;

  auto STAGE = [&](int h){
    int kt = h>>2, idx = h&3, par = kt&1;
    int koff = kt*64;
    if (idx < 2){
      const u16* s0 = Bb + (size_t)(idx*128 + rS0)*ldb + koff + cg;
      const u16* s1 = Bb + (size_t)(idx*128 + rS1)*ldb + koff + cg;
      u16* d = &lds8[par*32768 + 16384 + idx*8192];
      gload_lds16(s0, d + seg0);
      gload_lds16(s1, d + seg1);
    } else {
      int a = idx-2;
      const u16* s0 = Ab + (size_t)(a*128 + rS0)*lda + koff + cg;
      const u16* s1 = Ab + (size_t)(a*128 + rS1)*lda + koff + cg;
      u16* d = &lds8[par*32768 + a*8192];
      gload_lds16(s0, d + seg0);
      gload_lds16(s1, d + seg1);
    }
  };

  f32x4 acc[8][4];
  #pragma unroll
  for (int m=0;m<8;m++)
    #pragma unroll
    for (int n=0;n<4;n++) acc[m][n] = (f32x4){0.f,0.f,0.f,0.f};

  for (int h=0; h<7; ++h) STAGE(h);
  asm volatile("s_waitcnt vmcnt(6)" ::: "memory");
  __builtin_amdgcn_s_barrier();

  for (int it=0; it<NT/2; ++it){
    #pragma unroll
    for (int sub=0; sub<2; ++sub){
      int kt = it*2+sub;
      const int par = sub;
      u16* Abase = &lds8[par*32768 + wr*8192];
      u16* Bbase = &lds8[par*32768 + 16384 + (wc>>1)*8192];
      bf16x8 bf[4][2];
      #pragma unroll
      for (int q=0; q<4; ++q){
        bf16x8 af[2][2];
        if (q==0){
          #pragma unroll
          for (int n=0;n<4;n++)
            #pragma unroll
            for (int ss=0;ss<2;ss++){
              int rr = (wc&1)*64 + n*16 + (l&15);
              int c16 = (l>>4) + ss*4;
              bf[n][ss] = *(const bf16x8*)&Bbase[rr*64 + ((c16 ^ (rr&7))<<3)];
            }
        }
        #pragma unroll
        for (int i=0;i<2;i++)
          #pragma unroll
          for (int ss=0;ss<2;ss++){
            int rr = q*32 + i*16 + (l&15);
            int c16 = (l>>4) + ss*4;
            af[i][ss] = *(const bf16x8*)&Abase[rr*64 + ((c16 ^ (rr&7))<<3)];
          }
        __builtin_amdgcn_sched_barrier(0);
        int h = kt*4 + q + 7;
        if (h < 4*NT) STAGE(h);
        __builtin_amdgcn_s_barrier();
        asm volatile("s_waitcnt lgkmcnt(0)" ::: "memory");
        __builtin_amdgcn_sched_barrier(0);
        __builtin_amdgcn_s_setprio(1);
        #pragma unroll
        for (int i=0;i<2;i++)
          #pragma unroll
          for (int n=0;n<4;n++)
            #pragma unroll
            for (int ss=0;ss<2;ss++)
              acc[q*2+i][n] = __builtin_amdgcn_mfma_f32_16x16x32_bf16(af[i][ss], bf[n][ss], acc[q*2+i][n], 0, 0, 0);
        __builtin_amdgcn_s_setprio(0);
        if (q==3){
          if (kt == NT-2)      asm volatile("s_waitcnt vmcnt(0)" ::: "memory");
          else if (kt < NT-2)  asm volatile("s_waitcnt vmcnt(6)" ::: "memory");
        }
        __builtin_amdgcn_s_barrier();
      }
    }
  }

  size_t obase = (size_t)blockIdx.z*zC;
  int row0 = bx*256 + wr*128;
  int col0 = by*256 + wc*64;
  #pragma unroll
  for (int m=0;m<8;m++){
    #pragma unroll
    for (int n=0;n<4;n++){
      int col = col0 + n*16 + (l&15);
      #pragma unroll
      for (int r=0;r<4;r++){
        int row = row0 + m*16 + (l>>4)*4 + r;
        float c = acc[m][n][r];
        size_t idx = obase + (size_t)row*ldc + col;
        if (EPI==0){ ((u16*)outp)[idx] = f2bf(c); }
        else if (EPI==1){ ((u16*)outp)[idx] = f2bf(c + bias[col]); }
        else if (EPI==2){ float t=c+bias[col]; ((u16*)outp)[idx] = f2bf(bf2f(((const u16*)aux)[idx]) * sigm(t)); }
        else if (EPI==3){ float t=c+bias[col]; ((u16*)outp)[idx] = f2bf(t*sigm(t)); }
        else            { unsafeAtomicAdd(&((float*)outp)[idx], c); }
      }
    }
  }
}

// ---- 8-phase variant with z-selected epilogue: z=0 sigmoid-gate(bias)*aux, z=1 bias2 ----
template<int NT>
__global__ __launch_bounds__(512, 2)
void gemm8z(const u16* __restrict__ A, const u16* __restrict__ BT,
            void* __restrict__ outp, const float* __restrict__ bias,
            const float* __restrict__ bias2, const void* __restrict__ aux,
            int lda, int ldb, int ldc, long zA, long zB, long zC,
            int rx, int ry, int nry)
{
  __shared__ __attribute__((aligned(16))) u16 lds8[65536];
  int bid = blockIdx.y*gridDim.x + blockIdx.x;
  int xcd = bid & 7;
  int s   = bid >> 3;
  int rgx = xcd / nry, rgy = xcd - rgx*nry;
  int bx = rgx*rx + (s % rx);
  int by = rgy*ry + (s / rx);

  const u16* Ab = A + (size_t)blockIdx.z*zA + (size_t)bx*256*lda;
  const u16* Bb = BT + (size_t)blockIdx.z*zB + (size_t)by*256*ldb;

  int tid = threadIdx.x, l = tid&63, w = tid>>6;
  int wr = w>>2, wc = w&3;
  int rS0 = (w*2+0)*8 + (l>>3);
  int rS1 = (w*2+1)*8 + (l>>3);
  int cg  = (((l&7) ^ (l>>3)) << 3);
  int seg0 = (w*2+0)*512;
  int seg1 = (w*2+1)*512;

  auto STAGE = [&](int h){
    int kt = h>>2, idx = h&3, par = kt&1;
    int koff = kt*64;
    if (idx < 2){
      const u16* s0 = Bb + (size_t)(idx*128 + rS0)*ldb + koff + cg;
      const u16* s1 = Bb + (size_t)(idx*128 + rS1)*ldb + koff + cg;
      u16* d = &lds8[par*32768 + 16384 + idx*8192];
      gload_lds16(s0, d + seg0);
      gload_lds16(s1, d + seg1);
    } else {
      int a = idx-2;
      const u16* s0 = Ab + (size_t)(a*128 + rS0)*lda + koff + cg;
      const u16* s1 = Ab + (size_t)(a*128 + rS1)*lda + koff + cg;
      u16* d = &lds8[par*32768 + a*8192];
      gload_lds16(s0, d + seg0);
      gload_lds16(s1, d + seg1);
    }
  };

  f32x4 acc[8][4];
  #pragma unroll
  for (int m=0;m<8;m++)
    #pragma unroll
    for (int n=0;n<4;n++) acc[m][n] = (f32x4){0.f,0.f,0.f,0.f};

  for (int h=0; h<7; ++h) STAGE(h);
  asm volatile("s_waitcnt vmcnt(6)" ::: "memory");
  __builtin_amdgcn_s_barrier();

  for (int it=0; it<NT/2; ++it){
    #pragma unroll
    for (int sub=0; sub<2; ++sub){
      int kt = it*2+sub;
      const int par = sub;
      u16* Abase = &lds8[par*32768 + wr*8192];
      u16* Bbase = &lds8[par*32768 + 16384 + (wc>>1)*8192];
      bf16x8 bf[4][2];
      #pragma unroll
      for (int q=0; q<4; ++q){
        bf16x8 af[2][2];
        if (q==0){
          #pragma unroll
          for (int n=0;n<4;n++)
            #pragma unroll
            for (int ss=0;ss<2;ss++){
              int rr = (wc&1)*64 + n*16 + (l&15);
              int c16 = (l>>4) + ss*4;
              bf[n][ss] = *(const bf16x8*)&Bbase[rr*64 + ((c16 ^ (rr&7))<<3)];
            }
        }
        #pragma unroll
        for (int i=0;i<2;i++)
          #pragma unroll
          for (int ss=0;ss<2;ss++){
            int rr = q*32 + i*16 + (l&15);
            int c16 = (l>>4) + ss*4;
            af[i][ss] = *(const bf16x8*)&Abase[rr*64 + ((c16 ^ (rr&7))<<3)];
          }
        __builtin_amdgcn_sched_barrier(0);
        int h = kt*4 + q + 7;
        if (h < 4*NT) STAGE(h);
        __builtin_amdgcn_s_barrier();
        asm volatile("s_waitcnt lgkmcnt(0)" ::: "memory");
        __builtin_amdgcn_sched_barrier(0);
        __builtin_amdgcn_s_setprio(1);
        #pragma unroll
        for (int i=0;i<2;i++)
          #pragma unroll
          for (int n=0;n<4;n++)
            #pragma unroll
            for (int ss=0;ss<2;ss++)
              acc[q*2+i][n] = __builtin_amdgcn_mfma_f32_16x16x32_bf16(af[i][ss], bf[n][ss], acc[q*2+i][n], 0, 0, 0);
        __builtin_amdgcn_s_setprio(0);
        if (q==3){
          if (kt == NT-2)      asm volatile("s_waitcnt vmcnt(0)" ::: "memory");
          else if (kt < NT-2)  asm volatile("s_waitcnt vmcnt(6)" ::: "memory");
        }
        __builtin_amdgcn_s_barrier();
      }
    }
  }

  size_t obase = (size_t)blockIdx.z*zC;
  int row0 = bx*256 + wr*128;
  int col0 = by*256 + wc*64;
  bool z0 = (blockIdx.z == 0);
  #pragma unroll
  for (int m=0;m<8;m++){
    #pragma unroll
    for (int n=0;n<4;n++){
      int col = col0 + n*16 + (l&15);
      #pragma unroll
      for (int r=0;r<4;r++){
        int row = row0 + m*16 + (l>>4)*4 + r;
        float c = acc[m][n][r];
        size_t idx = obase + (size_t)row*ldc + col;
        if (z0){ float t=c+bias[col]; ((u16*)outp)[idx] = f2bf(bf2f(((const u16*)aux)[idx]) * sigm(t)); }
        else   { ((u16*)outp)[idx] = f2bf(c + bias2[col]); }
      }
    }
  }
}

// ---------------- 256x256 single-barrier-per-K-tile GEMM (NEW, race-free) ----------------
// Full next tile staged at K-tile start (8 loads, one tile of lead time);
// vmcnt(0)+barrier once per K-tile; compiler-scheduled ds_read/MFMA inside.
template<int NT, int EPI>
__global__ __launch_bounds__(512, 2)
void gemm2p(const u16* __restrict__ A, const u16* __restrict__ BT,
            void* __restrict__ outp, const float* __restrict__ bias,
            const void* __restrict__ aux,
            int lda, int ldb, int ldc, long zA, long zB, long zC,
            int rx, int ry, int nry)
{
  __shared__ __attribute__((aligned(16))) u16 lds8[65536];
  int bid = blockIdx.y*gridDim.x + blockIdx.x;
  int xcd = bid & 7;
  int s   = bid >> 3;
  int rgx = xcd / nry, rgy = xcd - rgx*nry;
  int bx = rgx*rx + (s % rx);
  int by = rgy*ry + (s / rx);

  const u16* Ab = A + (size_t)blockIdx.z*zA + (size_t)bx*256*lda;
  const u16* Bb = BT + (size_t)blockIdx.z*zB + (size_t)by*256*ldb;

  int tid = threadIdx.x, l = tid&63, w = tid>>6;
  int wr = w>>2, wc = w&3;
  int cg  = (((l&7) ^ (l>>3)) << 3);
  const u16* gA0 = Ab + (size_t)((w*2+0)*8 + (l>>3))*lda + cg;
  const u16* gA1 = Ab + (size_t)((w*2+1)*8 + (l>>3))*lda + cg;
  const u16* gB0 = Bb + (size_t)((w*2+0)*8 + (l>>3))*ldb + cg;
  const u16* gB1 = Bb + (size_t)((w*2+1)*8 + (l>>3))*ldb + cg;
  size_t a128 = (size_t)128*lda, b128 = (size_t)128*ldb;
  int seg0 = (w*2+0)*512, seg1 = (w*2+1)*512;

  auto STAGE_TILE = [&](int par){
    u16* Ad = &lds8[par*32768];
    u16* Bd = &lds8[par*32768 + 16384];
    gload_lds16(gB0,        Bd + seg0);
    gload_lds16(gB1,        Bd + seg1);
    gload_lds16(gB0 + b128, Bd + 8192 + seg0);
    gload_lds16(gB1 + b128, Bd + 8192 + seg1);
    gload_lds16(gA0,        Ad + seg0);
    gload_lds16(gA1,        Ad + seg1);
    gload_lds16(gA0 + a128, Ad + 8192 + seg0);
    gload_lds16(gA1 + a128, Ad + 8192 + seg1);
    gA0 += 64; gA1 += 64; gB0 += 64; gB1 += 64;
  };

  f32x4 acc[8][4];
  #pragma unroll
  for (int m=0;m<8;m++)
    #pragma unroll
    for (int n=0;n<4;n++) acc[m][n] = (f32x4){0.f,0.f,0.f,0.f};

  STAGE_TILE(0);
  asm volatile("s_waitcnt vmcnt(0)" ::: "memory");
  __builtin_amdgcn_s_barrier();
  __builtin_amdgcn_sched_barrier(0);

  for (int kt=0; kt<NT; ++kt){
    int par = kt&1;
    if (kt+1 < NT) STAGE_TILE(par^1);          // issue next tile FIRST (full tile of lead)
    u16* Abase = &lds8[par*32768 + wr*8192];
    u16* Bbase = &lds8[par*32768 + 16384 + (wc>>1)*8192];
    bf16x8 bf[4][2];
    #pragma unroll
    for (int n=0;n<4;n++)
      #pragma unroll
      for (int ss=0;ss<2;ss++){
        int rr = (wc&1)*64 + n*16 + (l&15);
        int c16 = (l>>4) + ss*4;
        bf[n][ss] = *(const bf16x8*)&Bbase[rr*64 + ((c16 ^ (rr&7))<<3)];
      }
    __builtin_amdgcn_s_setprio(1);
    #pragma unroll
    for (int q=0;q<4;q++){
      bf16x8 af[2][2];
      #pragma unroll
      for (int i=0;i<2;i++)
        #pragma unroll
        for (int ss=0;ss<2;ss++){
          int rr = q*32 + i*16 + (l&15);
          int c16 = (l>>4) + ss*4;
          af[i][ss] = *(const bf16x8*)&Abase[rr*64 + ((c16 ^ (rr&7))<<3)];
        }
      #pragma unroll
      for (int i=0;i<2;i++)
        #pragma unroll
        for (int n=0;n<4;n++)
          #pragma unroll
          for (int ss=0;ss<2;ss++)
            acc[q*2+i][n] = __builtin_amdgcn_mfma_f32_16x16x32_bf16(af[i][ss], bf[n][ss], acc[q*2+i][n], 0, 0, 0);
    }
    __builtin_amdgcn_s_setprio(0);
    asm volatile("s_waitcnt vmcnt(0)" ::: "memory");   // next tile landed (issued ~1 tile ago)
    __builtin_amdgcn_s_barrier();
    __builtin_amdgcn_sched_barrier(0);
  }

  size_t obase = (size_t)blockIdx.z*zC;
  int row0 = bx*256 + wr*128;
  int col0 = by*256 + wc*64;
  #pragma unroll
  for (int m=0;m<8;m++){
    #pragma unroll
    for (int n=0;n<4;n++){
      int col = col0 + n*16 + (l&15);
      #pragma unroll
      for (int r=0;r<4;r++){
        int row = row0 + m*16 + (l>>4)*4 + r;
        float c = acc[m][n][r];
        size_t idx = obase + (size_t)row*ldc + col;
        if (EPI==0){ ((u16*)outp)[idx] = f2bf(c); }
        else if (EPI==1){ ((u16*)outp)[idx] = f2bf(c + bias[col]); }
        else if (EPI==2){ float t=c+bias[col]; ((u16*)outp)[idx] = f2bf(bf2f(((const u16*)aux)[idx]) * sigm(t)); }
        else if (EPI==3){ float t=c+bias[col]; ((u16*)outp)[idx] = f2bf(t*sigm(t)); }
        else            { unsafeAtomicAdd(&((float*)outp)[idx], c); }
      }
    }
  }
}

// ---------------- decay-state scan, vectorized (CHS=64 chunks, 3 passes) ----------------
template<int KH>
__global__ __launch_bounds__(256) void scan_s1v(const u16* __restrict__ y, const float* __restrict__ logit,
                                                int p, float* __restrict__ Hend){
  int e0 = threadIdx.x*4;
  int c = blockIdx.y, b = blockIdx.z;
  float dec[KH]; f32x4 h[KH];
  #pragma unroll
  for (int k=0;k<KH;k++){ dec[k] = sigm(logit[KH*p+k]); h[k] = (f32x4){0.f,0.f,0.f,0.f}; }
  size_t row0 = (size_t)b*T_ + (size_t)c*CLS;
  for (int t=0;t<CLS;t++){
    const u16* yp = y + (row0+t)*(size_t)(KH*D_) + e0;
    #pragma unroll
    for (int k=0;k<KH;k++){
      u16x4 w = *(const u16x4*)(yp + (size_t)k*D_);
      #pragma unroll
      for (int j=0;j<4;j++) h[k][j] = dec[k]*h[k][j] + bf2f(w[j]);
    }
  }
  #pragma unroll
  for (int k=0;k<KH;k++)
    *(f32x4*)&Hend[(((size_t)b*CHS+c)*KH+k)*D_ + e0] = h[k];
}

template<int KH>
__global__ __launch_bounds__(256) void scan_s2v(const float* __restrict__ Hend, const float* __restrict__ logit,
                                                int p, float* __restrict__ Sinit){
  int idx = blockIdx.x*256 + threadIdx.x;
  if (idx >= B_*KH*D_) return;
  int e = idx % D_; int kh = (idx/D_) % KH; int b = idx/(D_*KH);
  float dec = sigm(logit[KH*p+kh]);
  float dL = powf(dec, (float)CLS);
  float carry = 0.f;
  for (int c=0;c<CHS;c++){
    size_t i3 = (((size_t)b*CHS+c)*KH+kh)*D_ + e;
    Sinit[i3] = carry;
    carry = dL*carry + Hend[i3];
  }
}

template<int KH>
__global__ __launch_bounds__(256) void scan_s3v(const u16* __restrict__ y, const float* __restrict__ logit,
                                                int p, const float* __restrict__ Sinit,
                                                const float* __restrict__ glb, float* __restrict__ out){
  int e0 = threadIdx.x*4;
  int c = blockIdx.y, b = blockIdx.z;
  float dec[KH]; f32x4 h[KH];
  #pragma unroll
  for (int k=0;k<KH;k++){
    dec[k] = sigm(logit[KH*p+k]);
    h[k] = *(const f32x4*)&Sinit[(((size_t)b*CHS+c)*KH+k)*D_ + e0];
  }
  size_t row0 = (size_t)b*T_ + (size_t)c*CLS;
  for (int t=0;t<CLS;t++){
    const u16* yp = y + (row0+t)*(size_t)(KH*D_) + e0;
    f32x4 sum = (f32x4){0.f,0.f,0.f,0.f};
    #pragma unroll
    for (int k=0;k<KH;k++){
      u16x4 w = *(const u16x4*)(yp + (size_t)k*D_);
      #pragma unroll
      for (int j=0;j<4;j++){ h[k][j] = dec[k]*h[k][j] + bf2f(w[j]); sum[j] += h[k][j]; }
    }
    float g = glb[row0+t];
    f32x4* op = (f32x4*)&out[(row0+t)*D_ + e0];
    f32x4 ov = *op;
    #pragma unroll
    for (int j=0;j<4;j++) ov[j] += g*sum[j];
    *op = ov;
  }
}

// ---------------- register scan (chunked, 3 passes) ----------------
__global__ __launch_bounds__(256) void scan_r1(const u16* __restrict__ v, const float* __restrict__ sel,
                                               const float* __restrict__ wg,
                                               float* __restrict__ Rend, float* __restrict__ Pout){
  int d = blockIdx.x*256 + threadIdx.x;
  int c = blockIdx.y, b = blockIdx.z;
  __shared__ float sel_s[CL*R_];
  __shared__ float wg_s[CL];
  size_t row0 = (size_t)b*T_ + (size_t)c*CL;
  for (int i=threadIdx.x; i<CL*R_; i+=256) sel_s[i] = sel[row0*R_ + i];
  for (int i=threadIdx.x; i<CL;    i+=256) wg_s[i]  = wg[row0 + i];
  __syncthreads();
  float regs[R_], P[R_];
  #pragma unroll
  for (int r=0;r<R_;r++){ regs[r]=0.f; P[r]=1.f; }
  for (int t=0;t<CL;t++){
    float vv = bf2f(v[(row0+t)*D_ + d]);
    float w = wg_s[t];
    #pragma unroll
    for (int r=0;r<R_;r++){
      float ws = w*sel_s[t*R_+r];
      regs[r] += ws*(vv - regs[r]);
      P[r] *= (1.f - ws);
    }
  }
  #pragma unroll
  for (int r=0;r<R_;r++) Rend[(((size_t)b*CH+c)*R_+r)*D_ + d] = regs[r];
  if (blockIdx.x==0 && threadIdx.x==0){
    #pragma unroll
    for (int r=0;r<R_;r++) Pout[((size_t)b*CH+c)*R_ + r] = P[r];
  }
}

__global__ __launch_bounds__(256) void scan_r2(const float* __restrict__ Rend, const float* __restrict__ Pbuf,
                                               float* __restrict__ Rinit){
  int idx = blockIdx.x*256 + threadIdx.x;
  if (idx >= B_*D_) return;
  int d = idx % D_; int b = idx / D_;
  float regs[R_];
  #pragma unroll
  for (int r=0;r<R_;r++) regs[r] = 0.f;
  for (int c=0;c<CH;c++){
    #pragma unroll
    for (int r=0;r<R_;r++){
      size_t i3 = (((size_t)b*CH+c)*R_+r)*D_ + d;
      Rinit[i3] = regs[r];
      regs[r] = Pbuf[((size_t)b*CH+c)*R_+r]*regs[r] + Rend[i3];
    }
  }
}

__global__ __launch_bounds__(256) void scan_r3(const u16* __restrict__ v, const float* __restrict__ sel,
                                               const float* __restrict__ wg, const float* __restrict__ Rinit,
                                               const float* __restrict__ grb, float* __restrict__ out){
  int d = blockIdx.x*256 + threadIdx.x;
  int c = blockIdx.y, b = blockIdx.z;
  __shared__ float sel_s[CL*R_];
  __shared__ float wg_s[CL];
  size_t row0 = (size_t)b*T_ + (size_t)c*CL;
  for (int i=threadIdx.x; i<CL*R_; i+=256) sel_s[i] = sel[row0*R_ + i];
  for (int i=threadIdx.x; i<CL;    i+=256) wg_s[i]  = wg[row0 + i];
  __syncthreads();
  float regs[R_];
  #pragma unroll
  for (int r=0;r<R_;r++) regs[r] = Rinit[(((size_t)b*CH+c)*R_+r)*D_ + d];
  for (int t=0;t<CL;t++){
    float vv = bf2f(v[(row0+t)*D_ + d]);
    float w = wg_s[t];
    float read = 0.f;
    #pragma unroll
    for (int r=0;r<R_;r++){
      float sr = sel_s[t*R_+r];
      read += sr*regs[r];
      float ws = w*sr;
      regs[r] += ws*(vv - regs[r]);
    }
    out[(row0+t)*D_ + d] += grb[row0+t]*read;
  }
}

// ---------------- host ----------------
static void launch_gemm(int epi, dim3 g, const u16* A, const u16* BT, void* out,
                        const float* bias, const void* aux, int K, int lda, int ldb, int ldc,
                        long zA, long zB, long zC, hipStream_t s){
  switch(epi){
    case 0: gemm_bt<0><<<g,256,0,s>>>(A,BT,out,bias,aux,K,lda,ldb,ldc,zA,zB,zC); break;
    case 1: gemm_bt<1><<<g,256,0,s>>>(A,BT,out,bias,aux,K,lda,ldb,ldc,zA,zB,zC); break;
    case 2: gemm_bt<2><<<g,256,0,s>>>(A,BT,out,bias,aux,K,lda,ldb,ldc,zA,zB,zC); break;
    case 3: gemm_bt<3><<<g,256,0,s>>>(A,BT,out,bias,aux,K,lda,ldb,ldc,zA,zB,zC); break;
    case 4: gemm_bt<4><<<g,256,0,s>>>(A,BT,out,bias,aux,K,lda,ldb,ldc,zA,zB,zC); break;
    default: gemm_bt<5><<<g,256,0,s>>>(A,BT,out,bias,aux,K,lda,ldb,ldc,zA,zB,zC); break;
  }
}

extern "C" void kernel_launch(void* const* d_in, const int* in_sizes, int n_in,
                              void* d_out, int out_size, void* d_ws, size_t ws_size,
                              hipStream_t stream){
  const float* x      = (const float*)d_in[0];
  const float* conv_w = (const float*)d_in[1];
  const float* gp_w   = (const float*)d_in[2];
  const float* gp_b   = (const float*)d_in[3];
  const float* up_w   = (const float*)d_in[4];
  const float* up_b   = (const float*)d_in[5];
  const float* dn_w   = (const float*)d_in[6];
  const float* dn_b   = (const float*)d_in[7];
  const float* si_w   = (const float*)d_in[8];
  const float* so_w   = (const float*)d_in[9];
  const float* logit  = (const float*)d_in[10];
  const float* rs_w   = (const float*)d_in[11];
  const float* rs_b   = (const float*)d_in[12];
  const float* rwg_w  = (const float*)d_in[13];
  const float* rwg_b  = (const float*)d_in[14];
  const float* rv_w   = (const float*)d_in[15];
  const float* rv_b   = (const float*)d_in[16];
  const float* gr_w   = (const float*)d_in[17];
  const float* gr_b   = (const float*)d_in[18];
  const float* gl_w   = (const float*)d_in[19];
  const float* gl_b   = (const float*)d_in[20];
  float* out = (float*)d_out;
  char* base = (char*)d_ws;

  // ---------- FULL layout (~173 MB; known to fit) ----------
  {
    size_t off = 0;
    auto al = [&](size_t b)->char*{ char* r = base+off; off += (b+255)&~(size_t)255; return r; };
    char* u_r    = al((size_t)NROW*D_*2);        // 16.8M
    char* v_r    = al((size_t)NROW*D_*2);        // 16.8M
    char* big    = al((size_t)121634816);        // phased region
    float* sel   = (float*)al((size_t)NROW*R_*4);
    float* wgb   = (float*)al((size_t)NROW*4);
    float* glb   = (float*)al((size_t)NROW*4);
    float* grb   = (float*)al((size_t)NROW*4);
    float* Pbuf  = (float*)al((size_t)B_*CH*R_*4);
    float* Rend  = (float*)al((size_t)B_*CH*R_*D_*4);
    float* Rinit = (float*)al((size_t)B_*CH*R_*D_*4);
    if (off <= ws_size){
      u16* u_bf  = (u16*)u_r;
      u16* v_bf  = (u16*)v_r;
      // phase-1 slots
      u16* hid   = (u16*)big;                                  // 67.1M (alive until dn)
      u16* xc_bf = (u16*)(big + (size_t)67108864);             // 16.8M
      u16* xg_bf = (u16*)(big + (size_t)83886080);             // 16.8M
      u16* gpT   = (u16*)(big + (size_t)100663296);            // 2.1M
      u16* upT   = (u16*)(big + (size_t)102760448);            // 8.4M
      u16* dnT   = (u16*)(big + (size_t)111149056);            // 8.4M
      u16* rvT   = (u16*)(big + (size_t)119537664);            // 2.1M
      // phase-2 slots (hid dead after dn)
      u16* WT    = (u16*)big;                                  // 16.8M
      u16* si_bf = (u16*)(big + (size_t)16777216);             // 16.8M
      u16* soT   = (u16*)(big + (size_t)33554432);             // 16.8M
      // phase-3 slots (si/soT dead; xg slot reused for scan temps)
      u16* y_bf  = (u16*)(big + (size_t)16777216);             // 67.1M -> ends 83.9M
      float* Hend  = (float*)(big + (size_t)83886080);         // 4.2M (xg slot)
      float* Sinit = (float*)(big + (size_t)88080384);         // 4.2M

      // weight prep
      transpose_cast<<<dim3(D_/32, D_/32),256,0,stream>>>(gp_w, gpT, D_, D_);
      transpose_cast<<<dim3(H_/32, D_/32),256,0,stream>>>(up_w, upT, D_, H_);
      transpose_cast<<<dim3(D_/32, H_/32),256,0,stream>>>(dn_w, dnT, H_, D_);
      transpose_cast<<<dim3(D_/32, D_/32),256,0,stream>>>(rv_w, rvT, D_, D_);

      // activations
      rmsnorm_k<<<NROW,256,0,stream>>>(x, u_bf);
      conv_k<<<(NROW*D_)/1024,256,0,stream>>>(u_bf, conv_w, xc_bf);
      smalln_k<<<NROW,256,0,stream>>>(u_bf, rs_w, rs_b, rwg_w, rwg_b, gl_w, gl_b, gr_w, gr_b,
                                      sel, wgb, glb, grb);

      // MERGED: z=0: xg = xc*sigm(xc@gp+gp_b);  z=1: v = u@rv + rv_b   (256 blocks)
      gemm8z<16><<<dim3(NROW/256, D_/256, 2), 512, 0, stream>>>(
          xc_bf, gpT, xg_bf, gp_b, rv_b, xc_bf, D_, D_, D_,
          (long)(u_bf - xc_bf), (long)(rvT - gpT), (long)(v_bf - xg_bf), 4, 4, 1);

      // hid = silu(xg@up_w + up_b)   --- NEW gemm2p (A/B experiment arm)
      gemm2p<16,3><<<dim3(NROW/256, H_/256), 512, 0, stream>>>(
          xg_bf, upT, hid, up_b, nullptr, D_, D_, H_, 0, 0, 0, 8, 8, 2);

      // out = x + dn_b ; out += hid@dn_w (split-K z=2, atomic combine)
      initout_k<<<(NROW*D_)/1024,256,0,stream>>>(x, dn_b, out);
      gemm8p<32,5><<<dim3(NROW/256, D_/256, 2), 512, 0, stream>>>(
          hid, dnT, out, nullptr, nullptr, H_, H_, D_, 2048, 2048, 0, 4, 4, 1);

      // W_k = si_k @ so_k (stored transposed), batched z=8
      transpose_cast<<<dim3(D_/32, (K_*D_)/32),256,0,stream>>>(so_w, soT, K_*D_, D_);
      castbf<<<((long)D_*K_*D_+255)/256,256,0,stream>>>(si_w, si_bf, (long)D_*K_*D_);
      gemm8p<16,0><<<dim3(D_/256, D_/256, K_), 512, 0, stream>>>(
          soT, si_bf, WT, nullptr, nullptr, K_*D_, K_*D_, D_, (long)D_, (long)D_, (long)D_*D_, 2, 1, 4);

      // long path in two k-halves (4 decays each) --- CONTROL arm (old 8-phase)
      for (int h=0; h<2; h++){
        gemm8p<16,0><<<dim3(NROW/256, (4*D_)/256), 512, 0, stream>>>(
            u_bf, WT + (size_t)h*4*D_*D_, y_bf, nullptr, nullptr, D_, D_, 4*D_, 0, 0, 0, 8, 8, 2);
        scan_s1v<4><<<dim3(1, CHS, B_),256,0,stream>>>(y_bf, logit, h, Hend);
        scan_s2v<4><<<(B_*4*D_+255)/256,256,0,stream>>>(Hend, logit, h, Sinit);
        scan_s3v<4><<<dim3(1, CHS, B_),256,0,stream>>>(y_bf, logit, h, Sinit, glb, out);
      }

      // register scan
      scan_r1<<<dim3(D_/256, CH, B_),256,0,stream>>>(v_bf, sel, wgb, Rend, Pbuf);
      scan_r2<<<(B_*D_+255)/256,256,0,stream>>>(Rend, Pbuf, Rinit);
      scan_r3<<<dim3(D_/256, CH, B_),256,0,stream>>>(v_bf, sel, wgb, Rinit, grb, out);
      return;
    }
  }

  // ---------- FALLBACK: round-2 layout (~94 MB, proven) ----------
  const size_t MB16_8 = (size_t)NROW*D_*2;
  size_t off = 0;
  auto alloc = [&](size_t bytes)->char*{
    char* r = base + off; off += (bytes + 255) & ~(size_t)255; return r;
  };
  char* R0 = alloc(MB16_8);
  char* R1 = alloc(MB16_8);
  char* R2 = alloc(2*MB16_8);
  char* R3 = alloc((size_t)21*1024*1024);
  float* sel  = (float*)alloc((size_t)NROW*R_*4);
  float* wgb  = (float*)alloc((size_t)NROW*4);
  float* glb  = (float*)alloc((size_t)NROW*4);
  float* grb  = (float*)alloc((size_t)NROW*4);
  float* Pbuf = (float*)alloc((size_t)B_*CH*R_*4);
  float* Hend = (float*)alloc((size_t)B_*CHS*2*D_*4);
  float* Sinit= (float*)alloc((size_t)B_*CHS*2*D_*4);
  if (off > ws_size){
    fill_k<<<((long)out_size+255)/256,256,0,stream>>>(out, out_size, 12345.0f);
    return;
  }

  u16* u_bf  = (u16*)R0;
  u16* v_bf  = (u16*)R1;
  u16* xc_bf = (u16*)R2;
  u16* xg_bf = (u16*)(R2 + MB16_8);
  u16* hid_bf= (u16*)R2;
  u16* soT   = (u16*)R2;
  u16* si_bf = (u16*)(R2 + MB16_8);
  u16* y_bf  = (u16*)R2;
  u16* gpT   = (u16*)R3;
  u16* upT   = (u16*)(R3 + (size_t)2*1024*1024 + 131072);
  u16* dnT   = (u16*)(R3 + (size_t)10*1024*1024 + 655360);
  u16* rvT   = (u16*)(R3 + (size_t)19*1024*1024);
  u16* WT    = (u16*)R3;
  float* Rend = (float*)R3;
  float* Rinit= (float*)(R3 + (size_t)NROW*D_);

  transpose_cast<<<dim3(D_/32, D_/32),256,0,stream>>>(gp_w, gpT, D_, D_);
  transpose_cast<<<dim3(H_/32, D_/32),256,0,stream>>>(up_w, upT, D_, H_);
  transpose_cast<<<dim3(D_/32, H_/32),256,0,stream>>>(dn_w, dnT, H_, D_);
  transpose_cast<<<dim3(D_/32, D_/32),256,0,stream>>>(rv_w, rvT, D_, D_);

  rmsnorm_k<<<NROW,256,0,stream>>>(x, u_bf);
  conv_k<<<(NROW*D_)/1024,256,0,stream>>>(u_bf, conv_w, xc_bf);
  smalln_k<<<NROW,256,0,stream>>>(u_bf, rs_w, rs_b, rwg_w, rwg_b, gl_w, gl_b, gr_w, gr_b,
                                  sel, wgb, glb, grb);

  launch_gemm(2, dim3(NROW/BM, D_/BN, 1), xc_bf, gpT, xg_bf, gp_b, xc_bf,
              D_, D_, D_, D_, 0, 0, 0, stream);
  launch_gemm(1, dim3(NROW/BM, D_/BN, 1), u_bf, rvT, v_bf, rv_b, nullptr,
              D_, D_, D_, D_, 0, 0, 0, stream);
  for (int q=0; q<4; q++){
    launch_gemm(3, dim3(NROW/BM, 1024/BN, 1), xg_bf, upT + (size_t)q*1024*D_, hid_bf,
                up_b + q*1024, nullptr, D_, D_, D_, 1024, 0, 0, 0, stream);
    launch_gemm(q==0?4:5, dim3(NROW/BM, D_/BN, 1), hid_bf, dnT + (size_t)q*1024, out,
                dn_b, x, 1024, 1024, H_, D_, 0, 0, 0, stream);
  }

  transpose_cast<<<dim3(D_/32, (K_*D_)/32),256,0,stream>>>(so_w, soT, K_*D_, D_);
  castbf<<<((long)D_*K_*D_+255)/256,256,0,stream>>>(si_w, si_bf, (long)D_*K_*D_);
  launch_gemm(0, dim3(D_/BM, D_/BN, K_), soT, si_bf, WT, nullptr, nullptr,
              D_, K_*D_, K_*D_, D_, (long)D_, (long)D_, (long)D_*D_, stream);

  for (int p=0; p<4; p++){
    launch_gemm(0, dim3(NROW/BM, (2*D_)/BN, 1), u_bf, WT + (size_t)(2*p)*D_*D_, y_bf,
                nullptr, nullptr, D_, D_, D_, 2*D_, 0, 0, 0, stream);
    scan_s1v<2><<<dim3(1, CHS, B_),256,0,stream>>>(y_bf, logit, p, Hend);
    scan_s2v<2><<<(B_*2*D_+255)/256,256,0,stream>>>(Hend, logit, p, Sinit);
    scan_s3v<2><<<dim3(1, CHS, B_),256,0,stream>>>(y_bf, logit, p, Sinit, glb, out);
  }

  scan_r1<<<dim3(D_/256, CH, B_),256,0,stream>>>(v_bf, sel, wgb, Rend, Pbuf);
  scan_r2<<<(B_*D_+255)/256,256,0,stream>>>(Rend, Pbuf, Rinit);
  scan_r3<<<dim3(D_/256, CH, B_),256,0,stream>>>(v_bf, sel, wgb, Rinit, grb, out);
}